// Round 3
// 428.072 us; speedup vs baseline: 1.0889x; 1.0889x over previous
//
#include <hip/hip_runtime.h>
#include <math.h>

#define NB 2
#define NN 2048
#define HIDDEN 2048
#define NHEAD 16
#define DHEAD 128

typedef __attribute__((ext_vector_type(8))) short bf16x8;
typedef __attribute__((ext_vector_type(4))) float floatx4;

static __device__ __forceinline__ short f2bf(float f) {
    union { float f; unsigned u; } v; v.f = f;
    unsigned r = v.u + 0x7fffu + ((v.u >> 16) & 1u);
    return (short)(r >> 16);
}
static __device__ __forceinline__ void gload_lds16(const short* g, short* l) {
    __builtin_amdgcn_global_load_lds(
        (const __attribute__((address_space(1))) void*)g,
        (__attribute__((address_space(3))) void*)l, 16, 0, 0);
}

// ---------------------------------------------------------------------------
// cast 3 fp32 arrays to bf16
// ---------------------------------------------------------------------------
__global__ __launch_bounds__(256) void cast_bf16_3(
    const float* __restrict__ a, const float* __restrict__ b, const float* __restrict__ c,
    short* __restrict__ oa, short* __restrict__ ob, short* __restrict__ oc,
    int n4a, int n4b, int n4c)
{
    int i = blockIdx.x * 256 + threadIdx.x;
    const float* s; short* d; int j;
    if (i < n4a) { s = a; d = oa; j = i; }
    else if (i < n4a + n4b) { s = b; d = ob; j = i - n4a; }
    else if (i < n4a + n4b + n4c) { s = c; d = oc; j = i - n4a - n4b; }
    else return;
    float4 v = ((const float4*)s)[j];
    short4 o;
    o.x = f2bf(v.x); o.y = f2bf(v.y); o.z = f2bf(v.z); o.w = f2bf(v.w);
    ((short4*)d)[j] = o;
}

// ---------------------------------------------------------------------------
// QKV GEMM, 256x256 tile / BK=64 / 8 waves (2Mx4N), 4-phase pipelined
// schedule with counted vmcnt (never 0 in loop), builtin s_barrier, setprio
// around MFMA clusters.  LDS 128 KB double-buffered:
//   [buf][ A 256x64 | B 256x64 ] bf16, row-major 128 B rows,
//   16B-chunk XOR swizzle j' = j ^ (row&7)  (stage: inverse-swizzled global
//   source + linear global_load_lds dest; read: swizzled ds_read_b128).
// B-frag columns: col(n) = n*64 + wc*16 + l15  (RoPE pairs (d,d+64) in one
// wave; 2 heads per 256-col block).
// Per-thread staging ledger (steady state), halves in order B0,A0,A1,B1:
//   enter iter with 8 outstanding (next tile's 4 halves)
//   P0: vmcnt(2) -> B0,A0,A1 valid; read A(m0-3),B(n0-1); stage B0(t+1)
//   P1: vmcnt(2) -> B1 valid;       read B(n2-3);         stage A0(t+1)
//   P2: barrier;                    read A(m4-7);         stage A1(t+1)
//   P3: barrier;                    (reuse B n0-1);       stage B1(t+1)
// Exit: s_waitcnt vmcnt(0) BEFORE epilogue — the last iteration's wrap
// prefetches are LDS-DMA; leaving them outstanding at s_endpgm lets the DMA
// write LDS after workgroup retirement (VM fault / queue wedge).
// ---------------------------------------------------------------------------
__global__ __launch_bounds__(512, 2) void gemm_qkv_256(
    const short* __restrict__ A, const short* __restrict__ Bw,
    const float* __restrict__ cosT, const float* __restrict__ sinT,
    short* __restrict__ Qp, short* __restrict__ Kp, short* __restrict__ Vtp)
{
    __shared__ __align__(16) short AB[65536];   // 128 KB

    const int tid = threadIdx.x;
    const int w = tid >> 6;
    const int l = tid & 63;
    const int quad = l >> 4;
    const int l15 = l & 15;
    const int wr = w >> 2;          // 0..1  M half
    const int wc = w & 3;           // 0..3  N 16-col band
    const int bm = blockIdx.y * 256;
    const int bn = blockIdx.x * 256;
    const int K = HIDDEN;

    // ---- staging sources/dests: 8 loads = {B0,A0,A1,B1} x {ld0,ld1}
    const short* src[8];
    int ldst[8];
#pragma unroll
    for (int ld = 0; ld < 2; ++ld) {
        int chunk = ld * 512 + tid;          // chunk within half (1024 of 16B)
        int row = chunk >> 3;                // 0..127
        int j = (chunk & 7) ^ (row & 7);     // inverse swizzle on global src
        int coff = j * 8;
        int dbase = chunk * 16;
        src[0 * 2 + ld] = Bw + (size_t)(bn + row) * K + coff;          // B half0
        src[1 * 2 + ld] = A  + (size_t)(bm + row) * K + coff;          // A half0
        src[2 * 2 + ld] = A  + (size_t)(bm + 128 + row) * K + coff;    // A half1
        src[3 * 2 + ld] = Bw + (size_t)(bn + 128 + row) * K + coff;    // B half1
        ldst[0 * 2 + ld] = 32768 + dbase;
        ldst[1 * 2 + ld] = 0 + dbase;
        ldst[2 * 2 + ld] = 16384 + dbase;
        ldst[3 * 2 + ld] = 32768 + 16384 + dbase;
    }

    // ---- frag-read invariants (row&7 == l15&7 for all frag rows)
    const int xj = l15 & 7;
    const int jq0 = ((0 * 4 + quad) ^ xj) * 16;   // kc=0 chunk byte off
    const int jq1 = ((1 * 4 + quad) ^ xj) * 16;   // kc=1
    const int arow = (wr * 128 + l15) * 128;      // + m*2048
    const int brow = (wc * 16 + l15) * 128;       // + 32768 + n*8192

    floatx4 acc[8][4];
#pragma unroll
    for (int i = 0; i < 8; ++i)
#pragma unroll
        for (int j = 0; j < 4; ++j) acc[i][j] = (floatx4){0.f, 0.f, 0.f, 0.f};

    // ---- prologue: stage tile 0 into buf0 (order B0,A0,A1,B1)
#pragma unroll
    for (int i = 0; i < 8; ++i)
        gload_lds16(src[i], (short*)((char*)AB + ldst[i]));

#define STAGE(i) gload_lds16(src[i] + kpf, (short*)((char*)AB + ldst[i] + so))
#define MFMA(d, x, y) d = __builtin_amdgcn_mfma_f32_16x16x32_bf16(x, y, d, 0, 0, 0)

    const int NT = K / 64;   // 32
#pragma unroll 1
    for (int t = 0; t < NT; ++t) {
        const int co = (t & 1) << 16;       // compute buffer
        const int so = co ^ 65536;          // stage buffer
        int kpf = (t + 1) * 64;
        if (kpf == K) kpf = 0;              // wrap: dummy prefetch (drained below)

        bf16x8 a[4][2], b0[2][2], b1[2][2];

        // ---------------- P0: Q(m0-3, n0-1)
        asm volatile("s_waitcnt vmcnt(2)" ::: "memory");
        __builtin_amdgcn_s_barrier();
#pragma unroll
        for (int m = 0; m < 4; ++m) {
            a[m][0] = *(const bf16x8*)((const char*)AB + co + arow + m * 2048 + jq0);
            a[m][1] = *(const bf16x8*)((const char*)AB + co + arow + m * 2048 + jq1);
        }
#pragma unroll
        for (int n = 0; n < 2; ++n) {
            b0[n][0] = *(const bf16x8*)((const char*)AB + co + 32768 + brow + n * 8192 + jq0);
            b0[n][1] = *(const bf16x8*)((const char*)AB + co + 32768 + brow + n * 8192 + jq1);
        }
        STAGE(0); STAGE(1);
        __builtin_amdgcn_s_setprio(1);
#pragma unroll
        for (int m = 0; m < 4; ++m)
#pragma unroll
            for (int n = 0; n < 2; ++n) {
                MFMA(acc[m][n], a[m][0], b0[n][0]);
                MFMA(acc[m][n], a[m][1], b0[n][1]);
            }
        __builtin_amdgcn_s_setprio(0);

        // ---------------- P1: Q(m0-3, n2-3)
        asm volatile("s_waitcnt vmcnt(2)" ::: "memory");
        __builtin_amdgcn_s_barrier();
#pragma unroll
        for (int n = 0; n < 2; ++n) {
            b1[n][0] = *(const bf16x8*)((const char*)AB + co + 32768 + 16384 + brow + n * 8192 + jq0);
            b1[n][1] = *(const bf16x8*)((const char*)AB + co + 32768 + 16384 + brow + n * 8192 + jq1);
        }
        STAGE(2); STAGE(3);
        __builtin_amdgcn_s_setprio(1);
#pragma unroll
        for (int m = 0; m < 4; ++m)
#pragma unroll
            for (int n = 0; n < 2; ++n) {
                MFMA(acc[m][2 + n], a[m][0], b1[n][0]);
                MFMA(acc[m][2 + n], a[m][1], b1[n][1]);
            }
        __builtin_amdgcn_s_setprio(0);

        // ---------------- P2: Q(m4-7, n2-3)
        __builtin_amdgcn_s_barrier();
#pragma unroll
        for (int m = 0; m < 4; ++m) {
            a[m][0] = *(const bf16x8*)((const char*)AB + co + arow + (4 + m) * 2048 + jq0);
            a[m][1] = *(const bf16x8*)((const char*)AB + co + arow + (4 + m) * 2048 + jq1);
        }
        STAGE(4); STAGE(5);
        __builtin_amdgcn_s_setprio(1);
#pragma unroll
        for (int m = 0; m < 4; ++m)
#pragma unroll
            for (int n = 0; n < 2; ++n) {
                MFMA(acc[4 + m][2 + n], a[m][0], b1[n][0]);
                MFMA(acc[4 + m][2 + n], a[m][1], b1[n][1]);
            }
        __builtin_amdgcn_s_setprio(0);

        // ---------------- P3: Q(m4-7, n0-1)  (reuse b0)
        __builtin_amdgcn_s_barrier();
        STAGE(6); STAGE(7);
        __builtin_amdgcn_s_setprio(1);
#pragma unroll
        for (int m = 0; m < 4; ++m)
#pragma unroll
            for (int n = 0; n < 2; ++n) {
                MFMA(acc[4 + m][n], a[m][0], b0[n][0]);
                MFMA(acc[4 + m][n], a[m][1], b0[n][1]);
            }
        __builtin_amdgcn_s_setprio(0);
    }
#undef STAGE
#undef MFMA

    // ---- drain wrap prefetches while LDS is still owned (see header note)
    asm volatile("s_waitcnt vmcnt(0)" ::: "memory");

    // ---- epilogue: RoPE q/k + scatter, V^T.  col(n) = n*64 + wc*16 + l15
    const int bx = blockIdx.x;
    const int which = bx >> 3;                 // 0=q 1=k 2=v
    const int hpair = (bx & 7) * 2;
    const float qsc = (which == 0) ? 0.12751791525f : 1.0f;  // 1/sqrt(128)*log2e

#pragma unroll
    for (int m = 0; m < 8; ++m) {
#pragma unroll
        for (int reg = 0; reg < 4; ++reg) {
            int gm = bm + wr * 128 + m * 16 + quad * 4 + reg;
            int b = gm >> 11, nseq = gm & (NN - 1);
            if (which == 2) {
#pragma unroll
                for (int n = 0; n < 4; ++n) {
                    int bh = b * NHEAD + hpair + (n >> 1);
                    int d = (n & 1) * 64 + wc * 16 + l15;
                    Vtp[((size_t)bh * DHEAD + d) * NN + nseq] = f2bf(acc[m][n][reg]);
                }
            } else {
                int d0 = wc * 16 + l15;        // < 64
                float c = cosT[(size_t)nseq * DHEAD + d0];
                float s = sinT[(size_t)nseq * DHEAD + d0];
#pragma unroll
                for (int hb = 0; hb < 2; ++hb) {
                    int bh = b * NHEAD + hpair + hb;
                    short* dst = (which == 0 ? Qp : Kp) + ((size_t)bh * NN + nseq) * DHEAD;
                    float e0 = acc[m][hb * 2 + 0][reg];
                    float e1 = acc[m][hb * 2 + 1][reg];
                    dst[d0]      = f2bf((e0 * c - e1 * s) * qsc);
                    dst[d0 + 64] = f2bf((e1 * c + e0 * s) * qsc);
                }
            }
        }
    }
}

// ---------------------------------------------------------------------------
// bf16 MFMA NT GEMM (kept for the output projection, MODE 1).
// ---------------------------------------------------------------------------
template <int MODE>
__global__ __launch_bounds__(256) void gemm_bf16_nt(
    const short* __restrict__ A, const short* __restrict__ Bw,
    const float* __restrict__ cosT, const float* __restrict__ sinT,
    short* __restrict__ Qp, short* __restrict__ Kp, short* __restrict__ Vtp,
    float* __restrict__ Cp, int M, int N, int K)
{
    __shared__ __align__(16) short AB[1280 * 8];   // 20.5 KB

    const int tid = threadIdx.x;
    const int w = tid >> 6;
    const int l = tid & 63;
    const int quad = l >> 4;
    const int l15 = l & 15;
    const int bm = blockIdx.y * 128;
    const int bn = blockIdx.x * 128;

    const int wm = (w & 1) * 64;
    const int wn2 = w >> 1;

    const short* gptr[5];
    short* lptr[5];
#pragma unroll
    for (int r5 = 0; r5 < 5; ++r5) {
        int s = r5 * 256 + tid;
        int m = (s < 640) ? s : s - 640;
        int row = m / 5;
        int ch = m - row * 5;
        if (ch == 4) ch = 0;
        gptr[r5] = ((s < 640) ? (A + (size_t)(bm + row) * K)
                              : (Bw + (size_t)(bn + row) * K)) + ch * 8;
        lptr[r5] = &AB[s * 8];
    }

    floatx4 acc[4][4];
#pragma unroll
    for (int i = 0; i < 4; ++i)
#pragma unroll
        for (int j = 0; j < 4; ++j) acc[i][j] = (floatx4){0.f, 0.f, 0.f, 0.f};

    for (int k0 = 0; k0 < K; k0 += 32) {
        __syncthreads();
#pragma unroll
        for (int r5 = 0; r5 < 5; ++r5)
            gload_lds16(gptr[r5] + k0, lptr[r5]);
        __syncthreads();

        bf16x8 af[4], bf[4];
#pragma unroll
        for (int i = 0; i < 4; ++i)
            af[i] = *(const bf16x8*)&AB[((wm + i * 16 + l15) * 5 + quad) * 8];
#pragma unroll
        for (int j = 0; j < 4; ++j) {
            int col = wn2 * 32 + (j & 1) * 16 + ((j >> 1) << 6);
            bf[j] = *(const bf16x8*)&AB[(640 + (col + l15) * 5 + quad) * 8];
        }
#pragma unroll
        for (int i = 0; i < 4; ++i)
#pragma unroll
            for (int j = 0; j < 4; ++j)
                acc[i][j] = __builtin_amdgcn_mfma_f32_16x16x32_bf16(af[i], bf[j], acc[i][j], 0, 0, 0);
    }

    if (MODE == 1) {
#pragma unroll
        for (int i = 0; i < 4; ++i) {
#pragma unroll
            for (int reg = 0; reg < 4; ++reg) {
                int row = bm + wm + i * 16 + quad * 4 + reg;
                float* crow = Cp + (size_t)row * N + bn;
#pragma unroll
                for (int j = 0; j < 4; ++j)
                    crow[wn2 * 32 + (j & 1) * 16 + ((j >> 1) << 6) + l15] = acc[i][j][reg];
            }
        }
    } else {
        const int which = bn >> 11;
        const int head = (bn >> 7) & (NHEAD - 1);
        const float qsc = (which == 0) ? 0.12751791525f : 1.0f;
#pragma unroll
        for (int i = 0; i < 4; ++i) {
#pragma unroll
            for (int reg = 0; reg < 4; ++reg) {
                int m = bm + wm + i * 16 + quad * 4 + reg;
                int b = m >> 11, n = m & (NN - 1);
                int bh = b * NHEAD + head;
                if (which == 2) {
#pragma unroll
                    for (int j = 0; j < 4; ++j) {
                        int d = wn2 * 32 + (j & 1) * 16 + ((j >> 1) << 6) + l15;
                        Vtp[((size_t)bh * DHEAD + d) * NN + n] = f2bf(acc[i][j][reg]);
                    }
                } else {
                    short* dst = (which == 0 ? Qp : Kp) + ((size_t)bh * NN + n) * DHEAD;
#pragma unroll
                    for (int j = 0; j < 2; ++j) {
                        int d0 = wn2 * 32 + j * 16 + l15;
                        float c = cosT[(size_t)n * DHEAD + d0];
                        float s = sinT[(size_t)n * DHEAD + d0];
                        float e0 = acc[i][j][reg], e1 = acc[i][j + 2][reg];
                        dst[d0]      = f2bf((e0 * c - e1 * s) * qsc);
                        dst[d0 + 64] = f2bf((e1 * c + e0 * s) * qsc);
                    }
                }
            }
        }
    }
}

// ---------------------------------------------------------------------------
// MFMA flash attention, R6: 4 waves x 32 Q-rows = 128 Q-rows/block.
// ---------------------------------------------------------------------------
__global__ __launch_bounds__(256, 2) void attn_mfma(
    const short* __restrict__ Qb, const short* __restrict__ Kb,
    const short* __restrict__ Vt, short* __restrict__ AOb)
{
    __shared__ __align__(16) short Ks[64 * 128];    // 16 KB, swizzle (s&15)^(row&15)
    __shared__ __align__(16) short Vs[128 * 64];    // 16 KB, swizzle (s&7)^(row&7)
    __shared__ __align__(16) short Ps[4][32][72];   // 18.4 KB bf16

    const int tid = threadIdx.x;
    const int w = tid >> 6;
    const int l = tid & 63;
    const int quad = l >> 4;
    const int l15 = l & 15;
    const int bh = blockIdx.y;
    const int qt = blockIdx.x * 128;

    const short* Qg = Qb + (size_t)bh * NN * DHEAD;
    const short* Kg = Kb + (size_t)bh * NN * DHEAD;
    const short* Vg = Vt + (size_t)bh * DHEAD * NN;

    bf16x8 qf[2][4];
#pragma unroll
    for (int mi = 0; mi < 2; ++mi) {
        const short* qrow = Qg + (size_t)(qt + w * 32 + mi * 16 + l15) * DHEAD + quad * 8;
#pragma unroll
        for (int kc = 0; kc < 4; ++kc) qf[mi][kc] = *(const bf16x8*)(qrow + kc * 32);
    }

    floatx4 of[2][8];
#pragma unroll
    for (int mi = 0; mi < 2; ++mi)
#pragma unroll
        for (int dc = 0; dc < 8; ++dc) of[mi][dc] = (floatx4){0.f, 0.f, 0.f, 0.f};
    float ls[2][4] = {{0.f, 0.f, 0.f, 0.f}, {0.f, 0.f, 0.f, 0.f}};

    for (int kt = 0; kt < NN; kt += 64) {
        __syncthreads();
#pragma unroll
        for (int rr = 0; rr < 4; ++rr) {
            int s = (w * 4 + rr) * 64 + l;
            int row = s >> 4;
            int j = (s & 15) ^ (row & 15);
            gload_lds16(Kg + (size_t)(kt + row) * DHEAD + j * 8, &Ks[s * 8]);
        }
#pragma unroll
        for (int rr = 0; rr < 4; ++rr) {
            int s = (w * 4 + rr) * 64 + l;
            int row = s >> 3;
            int c = (s & 7) ^ (row & 7);
            gload_lds16(Vg + (size_t)row * NN + kt + c * 8, &Vs[s * 8]);
        }
        __syncthreads();

        floatx4 sf[2][4];
#pragma unroll
        for (int n16 = 0; n16 < 4; ++n16) {
            bf16x8 kf[4];
            const short* kbase = &Ks[(n16 * 16 + l15) * 128];
#pragma unroll
            for (int kc = 0; kc < 4; ++kc)
                kf[kc] = *(const bf16x8*)&kbase[((4 * kc + quad) ^ l15) * 8];
#pragma unroll
            for (int mi = 0; mi < 2; ++mi) {
                floatx4 acc = (floatx4){0.f, 0.f, 0.f, 0.f};
#pragma unroll
                for (int kc = 0; kc < 4; ++kc)
                    acc = __builtin_amdgcn_mfma_f32_16x16x32_bf16(qf[mi][kc], kf[kc], acc, 0, 0, 0);
                sf[mi][n16] = acc;
            }
        }

#pragma unroll
        for (int mi = 0; mi < 2; ++mi)
#pragma unroll
            for (int n16 = 0; n16 < 4; ++n16)
#pragma unroll
                for (int r = 0; r < 4; ++r) {
                    float p = exp2f(sf[mi][n16][r]);
                    ls[mi][r] += p;
                    Ps[w][mi * 16 + quad * 4 + r][n16 * 16 + l15] = f2bf(p);
                }

        bf16x8 pa[2][2];
#pragma unroll
        for (int mi = 0; mi < 2; ++mi)
#pragma unroll
            for (int kc = 0; kc < 2; ++kc)
                pa[mi][kc] = *(const bf16x8*)&Ps[w][mi * 16 + l15][kc * 32 + quad * 8];

#pragma unroll
        for (int dc = 0; dc < 8; ++dc) {
            int row = dc * 16 + l15;
#pragma unroll
            for (int kc = 0; kc < 2; ++kc) {
                bf16x8 vf = *(const bf16x8*)&Vs[row * 64 + (((kc * 4 + quad) ^ (row & 7)) * 8)];
#pragma unroll
                for (int mi = 0; mi < 2; ++mi)
                    of[mi][dc] = __builtin_amdgcn_mfma_f32_16x16x32_bf16(
                                     pa[mi][kc], vf, of[mi][dc], 0, 0, 0);
            }
        }
    }

    const int b = bh >> 4, h = bh & (NHEAD - 1);
#pragma unroll
    for (int mi = 0; mi < 2; ++mi)
#pragma unroll
        for (int r = 0; r < 4; ++r) {
            float s = ls[mi][r];
            s += __shfl_xor(s, 1, 64);
            s += __shfl_xor(s, 2, 64);
            s += __shfl_xor(s, 4, 64);
            s += __shfl_xor(s, 8, 64);
            float inv = 1.0f / s;
            int row = qt + w * 32 + mi * 16 + quad * 4 + r;
            short* dst = AOb + ((size_t)(b * NN + row)) * HIDDEN + h * DHEAD;
#pragma unroll
            for (int dc = 0; dc < 8; ++dc)
                dst[dc * 16 + l15] = f2bf(of[mi][dc][r] * inv);
        }
}

// ---------------------------------------------------------------------------
extern "C" void kernel_launch(void* const* d_in, const int* in_sizes, int n_in,
                              void* d_out, int out_size, void* d_ws, size_t ws_size,
                              hipStream_t stream)
{
    const float* hs = (const float*)d_in[0];
    const float* cosT = (const float*)d_in[1];
    const float* sinT = (const float*)d_in[2];
    const float* wqkv = (const float*)d_in[3];
    const float* wo = (const float*)d_in[4];
    float* out = (float*)d_out;

    const size_t N_HS = (size_t)NB * NN * HIDDEN;
    const size_t N_WQ = (size_t)3 * HIDDEN * HIDDEN;
    const size_t N_WO = (size_t)HIDDEN * HIDDEN;
    const size_t SZ = (size_t)NB * NHEAD * NN * DHEAD;

    short* Ahs   = (short*)d_ws;
    short* Wqkvb = Ahs + N_HS;
    short* Wob   = Wqkvb + N_WQ;
    short* Qb    = Wob + N_WO;
    short* Kb    = Qb + SZ;
    short* Vtb   = Kb + SZ;
    short* AOb   = Vtb + SZ;

    {
        int n4a = (int)(N_HS / 4), n4b = (int)(N_WQ / 4), n4c = (int)(N_WO / 4);
        int total = n4a + n4b + n4c;
        cast_bf16_3<<<(total + 255) / 256, 256, 0, stream>>>(
            hs, wqkv, wo, Ahs, Wqkvb, Wob, n4a, n4b, n4c);
    }
    {
        dim3 grid(3 * HIDDEN / 256, NB * NN / 256);   // (24, 16)
        gemm_qkv_256<<<grid, 512, 0, stream>>>(
            Ahs, Wqkvb, cosT, sinT, Qb, Kb, Vtb);
    }
    {
        dim3 grid(NN / 128, NB * NHEAD);   // (16, 32)
        attn_mfma<<<grid, 256, 0, stream>>>(Qb, Kb, Vtb, AOb);
    }
    {
        dim3 grid(HIDDEN / 128, NB * NN / 128);   // (16, 32)
        gemm_bf16_nt<1><<<grid, 256, 0, stream>>>(
            AOb, Wob, nullptr, nullptr, nullptr, nullptr, nullptr, out,
            NB * NN, HIDDEN, HIDDEN);
    }
}